// Round 5
// baseline (254.223 us; speedup 1.0000x reference)
//
#include <hip/hip_runtime.h>

#define BB 128
#define TT 256
#define DDIM 64
#define NDP 516        // diag slots; 0..510 real, 511..515 zero pads (never written)
#define BIGF 1e10f
#define NEGB -1e12f
#define KE 144.2695040889f     // 1/(gamma*ln2)
#define GLN2 0.0069314718056f  // gamma*ln2

// Diagonal-layout scratch: [b][diag][row].
__device__ float  g_D [(size_t)BB * NDP * TT];
__device__ float2 g_RD[(size_t)BB * NDP * TT];   // {R, (R-D)*KE}
__device__ float  g_sumE[BB];
__device__ float  g_sumEw[BB];

__device__ __forceinline__ float ex2(float x){ float r; asm("v_exp_f32 %0, %1":"=v"(r):"v"(x)); return r; }
__device__ __forceinline__ float lg2(float x){ float r; asm("v_log_f32 %0, %1":"=v"(r):"v"(x)); return r; }
__device__ __forceinline__ float min3f(float a,float b,float c){ float r; asm("v_min3_f32 %0,%1,%2,%3":"=v"(r):"v"(a),"v"(b),"v"(c)); return r; }
__device__ __forceinline__ float med3f(float a,float b,float c){ float r; asm("v_med3_f32 %0,%1,%2,%3":"=v"(r):"v"(a),"v"(b),"v"(c)); return r; }
__device__ __forceinline__ float max3f(float a,float b,float c){ float r; asm("v_max3_f32 %0,%1,%2,%3":"=v"(r):"v"(a),"v"(b),"v"(c)); return r; }

// ---------------------------------------------------------------------------
// Kernel 1: pairwise squared distances, written in diagonal layout.
// ---------------------------------------------------------------------------
__global__ __launch_bounds__(256) void dist_kernel(const float* __restrict__ P,
                                                   const float* __restrict__ Q) {
    const int rt = blockIdx.x;
    const int ct = blockIdx.y;
    const int b  = blockIdx.z;
    const int tid = threadIdx.x;

    __shared__ float Pl[64][68];
    __shared__ float Tl[64][68];

    const float* Pbase = P + ((size_t)b * TT + rt * 64) * DDIM;
    const float* Qbase = Q + ((size_t)b * TT + ct * 64) * DDIM;

#pragma unroll
    for (int it = 0; it < 4; ++it) {
        int e = (tid + it * 256) * 4;
        int r = e >> 6;
        int k = e & 63;
        float4 pv = *reinterpret_cast<const float4*>(Pbase + e);
        float4 qv = *reinterpret_cast<const float4*>(Qbase + e);
        Pl[k + 0][r] = pv.x; Pl[k + 1][r] = pv.y; Pl[k + 2][r] = pv.z; Pl[k + 3][r] = pv.w;
        Tl[k + 0][r] = qv.x; Tl[k + 1][r] = qv.y; Tl[k + 2][r] = qv.z; Tl[k + 3][r] = qv.w;
    }
    __syncthreads();

    const int r0 = (tid >> 4) * 4;
    const int c0 = (tid & 15) * 4;

    float acc[4][4] = {};
#pragma unroll
    for (int k = 0; k < 64; ++k) {
        float4 p = *reinterpret_cast<const float4*>(&Pl[k][r0]);
        float4 t = *reinterpret_cast<const float4*>(&Tl[k][c0]);
        float pa[4] = {p.x, p.y, p.z, p.w};
        float ta[4] = {t.x, t.y, t.z, t.w};
#pragma unroll
        for (int a = 0; a < 4; ++a)
#pragma unroll
            for (int c = 0; c < 4; ++c) {
                float df = pa[a] - ta[c];
                acc[a][c] = fmaf(df, df, acc[a][c]);
            }
    }

    float* Dg = g_D + (size_t)b * NDP * TT;
#pragma unroll
    for (int a = 0; a < 4; ++a)
#pragma unroll
        for (int c = 0; c < 4; ++c) {
            int i = rt * 64 + r0 + a;
            int j = ct * 64 + c0 + c;
            Dg[(size_t)(i + j) * TT + i] = acc[a][c];
        }
}

// ---------------------------------------------------------------------------
// Kernel 2: fused soft-DTW fwd+bwd. One wave per batch, rows 4l..4l+3 per
// lane. SYSTOLIC SKEW: at tick t, lane l processes diag d = t - l (bwd:
// d = 573 - t - l). Cross-lane shfl has 2 ticks of slack -> off the chain;
// the 4 cells per tick are mutually independent -> 4-way ILP, issue-bound.
// No LDS, no barriers. Validity value-encoded (BIG / NEGB / zero-pads).
// ---------------------------------------------------------------------------
__global__ __launch_bounds__(64) void scan_kernel() {
    const int b    = blockIdx.x;
    const int lane = threadIdx.x;
    const int row0 = lane << 2;
    const bool lane0  = (lane == 0);
    const bool lane63 = (lane == 63);

    const float* Db  = g_D  + (size_t)b * NDP * TT;
    float2*      RDb = g_RD + (size_t)b * NDP * TT;

    // ---------------- forward ----------------
    float Rp1[4], Rp2[4];           // own rows at diag d-1 / d-2
#pragma unroll
    for (int r = 0; r < 4; ++r) { Rp1[r] = BIGF; Rp2[r] = BIGF; }
    float pf[2] = {BIGF, BIGF};     // in-flight shfl ring (2 ticks deep)
    float u1 = BIGF, u2 = BIGF;     // lane l-1 row-3 R at diag d-1 / d-2

    auto loadDq = [&](int t) -> float4 {
        int d = t - lane;
        d = d < 0 ? 0 : (d > 515 ? 515 : d);
        return *reinterpret_cast<const float4*>(Db + (size_t)d * TT + row0);
    };

    int dcur = -lane;

    auto FTICK = [&](const float4& dq, int kp) {
        u2 = u1;
        u1 = lane0 ? BIGF : pf[kp];         // consume shfl issued 2 ticks ago
        const float dv[4] = {dq.x, dq.y, dq.z, dq.w};
        float Rn[4], st[8];
#pragma unroll
        for (int r = 0; r < 4; ++r) {
            const float z1 = (r == 0) ? u2 : Rp2[r - 1];   // R[i-1][j-1]
            const float z2 = (r == 0) ? u1 : Rp1[r - 1];   // R[i-1][j]
            const float z3 = Rp1[r];                       // R[i][j-1]
            const float m  = min3f(z1, z2, z3);
            const float md = med3f(z1, z2, z3);
            const float mx = max3f(z1, z2, z3);
            const float mk = m * KE;
            const float s  = 1.0f + ex2(fmaf(md, -KE, mk)) + ex2(fmaf(mx, -KE, mk));
            float rv = dv[r] + fmaf(lg2(s), -GLN2, m);
            if (r == 0) rv = (dcur == 0 && lane0) ? dv[0] : rv;   // R[0][0]=D[0][0]
            const int j = dcur - (row0 + r);
            const bool valid = ((unsigned)j < 256u);
            Rn[r] = valid ? rv : BIGF;
            st[2 * r]     = Rn[r];
            st[2 * r + 1] = valid ? (rv - dv[r]) * KE : NEGB;
        }
#pragma unroll
        for (int r = 0; r < 4; ++r) { Rp2[r] = Rp1[r]; Rp1[r] = Rn[r]; }
        pf[kp] = __shfl_up(Rp1[3], 1);      // issue; consumed at tick t+2
        if ((unsigned)dcur <= 510u) {
            float4* sp = reinterpret_cast<float4*>(RDb + (size_t)dcur * TT + row0);
            sp[0] = make_float4(st[0], st[1], st[2], st[3]);
            sp[1] = make_float4(st[4], st[5], st[6], st[7]);
        }
        ++dcur;
    };

    {
        float4 qa[8], qb[8];
#pragma unroll
        for (int k = 0; k < 8; ++k) qa[k] = loadDq(k);
#pragma unroll 1
        for (int g = 0; g < 36; ++g) {      // 576 ticks
            const int t0 = g * 16;
#pragma unroll
            for (int k = 0; k < 8; ++k) qb[k] = loadDq(t0 + 8 + k);
            __builtin_amdgcn_sched_barrier(0);
#pragma unroll
            for (int k = 0; k < 8; ++k) FTICK(qa[k], k & 1);
#pragma unroll
            for (int k = 0; k < 8; ++k) qa[k] = loadDq(t0 + 16 + k);
            __builtin_amdgcn_sched_barrier(0);
#pragma unroll
            for (int k = 0; k < 8; ++k) FTICK(qb[k], k & 1);
        }
    }

    asm volatile("s_waitcnt vmcnt(0)" ::: "memory");   // fwd stores visible

    // ---------------- backward ----------------
    float Ep1[4], Ap1[4], Ep2[4], Ap2[4];   // own rows at diag d+1 / d+2
#pragma unroll
    for (int r = 0; r < 4; ++r) { Ep1[r] = 0.0f; Ap1[r] = NEGB; Ep2[r] = 0.0f; Ap2[r] = NEGB; }
    float pfE[2] = {0.0f, 0.0f}, pfA[2] = {NEGB, NEGB};
    float eu1 = 0.0f, au1 = NEGB, eu2 = 0.0f, au2 = NEGB;  // lane l+1 row-0 at d+1/d+2
    float sumE = 0.0f, sumEw = 0.0f;

    auto loadRDq = [&](int t, float4& lo, float4& hi) {
        int d = 573 - t - lane;
        d = d < 0 ? 0 : (d > 515 ? 515 : d);
        const float4* p = reinterpret_cast<const float4*>(RDb + (size_t)d * TT + row0);
        lo = p[0]; hi = p[1];
    };

    int db = 573 - lane;

    auto BTICK = [&](const float4& lo, const float4& hi, int kp) {
        eu2 = eu1; au2 = au1;
        eu1 = lane63 ? 0.0f : pfE[kp];
        au1 = lane63 ? NEGB : pfA[kp];
        const float Rc[4] = {lo.x, lo.z, hi.x, hi.z};
        const float Ac[4] = {lo.y, lo.w, hi.y, hi.w};
        float En[4];
#pragma unroll
        for (int r = 0; r < 4; ++r) {
            const float mi  = Rc[r] * KE;
            const float s1e = (r < 3) ? Ep1[r + 1] : eu1;   // (i+1, j)   d+1
            const float s1a = (r < 3) ? Ap1[r + 1] : au1;
            const float s2e = Ep1[r];                       // (i, j+1)   d+1
            const float s2a = Ap1[r];
            const float s3e = (r < 3) ? Ep2[r + 1] : eu2;   // (i+1, j+1) d+2
            const float s3a = (r < 3) ? Ap2[r + 1] : au2;
            float E = s1e * ex2(s1a - mi);
            E = fmaf(s2e, ex2(s2a - mi), E);
            E = fmaf(s3e, ex2(s3a - mi), E);
            if (r == 3) E = (db == 510 && lane63) ? 1.0f : E;  // seed (255,255)
            En[r] = E;
        }
        const bool live = (db >= 0);
#pragma unroll
        for (int r = 0; r < 4; ++r) {
            const float Eg = live ? En[r] : 0.0f;
            sumE += Eg;
            const float w = (float)(2 * (row0 + r) - db);
            sumEw = fmaf(Eg * w, w, sumEw);
            Ep2[r] = Ep1[r]; Ap2[r] = Ap1[r];
            Ep1[r] = Eg;     Ap1[r] = Ac[r];
        }
        pfE[kp] = __shfl_down(Ep1[0], 1);
        pfA[kp] = __shfl_down(Ap1[0], 1);
        --db;
    };

    {
        float4 ral[8], rah[8], rbl[8], rbh[8];
#pragma unroll
        for (int k = 0; k < 8; ++k) loadRDq(k, ral[k], rah[k]);
#pragma unroll 1
        for (int g = 0; g < 36; ++g) {      // 576 ticks
            const int t0 = g * 16;
#pragma unroll
            for (int k = 0; k < 8; ++k) loadRDq(t0 + 8 + k, rbl[k], rbh[k]);
            __builtin_amdgcn_sched_barrier(0);
#pragma unroll
            for (int k = 0; k < 8; ++k) BTICK(ral[k], rah[k], k & 1);
#pragma unroll
            for (int k = 0; k < 8; ++k) loadRDq(t0 + 16 + k, ral[k], rah[k]);
            __builtin_amdgcn_sched_barrier(0);
#pragma unroll
            for (int k = 0; k < 8; ++k) BTICK(rbl[k], rbh[k], k & 1);
        }
    }

    // wave reduction
#pragma unroll
    for (int off = 32; off; off >>= 1) {
        sumE  += __shfl_xor(sumE,  off);
        sumEw += __shfl_xor(sumEw, off);
    }
    if (lane == 0) { g_sumE[b] = sumE; g_sumEw[b] = sumEw; }
}

// ---------------------------------------------------------------------------
// Kernel 3: finalize scalar loss.
// ---------------------------------------------------------------------------
__global__ __launch_bounds__(128) void fin_kernel(float* __restrict__ out) {
    __shared__ float rs[128];
    __shared__ float rt2[128];
    const int b = threadIdx.x;

    const float rfin = g_RD[((size_t)b * NDP + 510) * TT + (TT - 1)].x;
    const float shape = rfin * (1.0f / (float)TT);

    const float sE  = g_sumE[b]  * (1.0f / (float)TT);
    const float sEw = g_sumEw[b] * (1.0f / (float)TT) * (1.0f / (255.0f * 255.0f));
    const float temporal = sEw / fmaxf(sE, 1e-8f);

    rs[b]  = shape;
    rt2[b] = temporal;
    __syncthreads();
    for (int s = 64; s > 0; s >>= 1) {
        if (b < s) { rs[b] += rs[b + s]; rt2[b] += rt2[b + s]; }
        __syncthreads();
    }
    if (b == 0) {
        out[0] = 0.5f * (rs[0] * (1.0f / (float)BB)) + 0.5f * (rt2[0] * (1.0f / (float)BB));
    }
}

extern "C" void kernel_launch(void* const* d_in, const int* in_sizes, int n_in,
                              void* d_out, int out_size, void* d_ws, size_t ws_size,
                              hipStream_t stream) {
    (void)in_sizes; (void)n_in; (void)out_size; (void)d_ws; (void)ws_size;
    const float* preds   = (const float*)d_in[0];
    const float* targets = (const float*)d_in[1];
    float* out = (float*)d_out;

    dist_kernel<<<dim3(4, 4, BB), 256, 0, stream>>>(preds, targets);
    scan_kernel<<<BB, 64, 0, stream>>>();
    fin_kernel<<<1, 128, 0, stream>>>(out);
}